// Round 1
// baseline (257.065 us; speedup 1.0000x reference)
//
#include <hip/hip_runtime.h>

// Problem constants (from reference)
#define BATCH 128
#define SEQ   2000
#define EMB   50
#define OUTD  2

// Tiling
#define CHUNKS 8                       // seq chunks per batch row
#define SPB    ((SEQ + CHUNKS - 1) / CHUNKS)   // 250 indices per block
#define TPB    256
#define WAVES  (TPB / 64)

// Kernel 1: each block = (chunk c, batch b). Each thread handles one index,
// gathers its 50-float embedding row as 25 float2 loads, and immediately
// folds the 50->2 linear layer (W staged in LDS, broadcast reads).
// Block-reduces the 2 scalars and writes a partial to ws.
__global__ __launch_bounds__(TPB) void embbag_partial_kernel(
    const int* __restrict__ t,          // [BATCH, SEQ]
    const float* __restrict__ emb,      // [VOCAB, EMB]
    const float* __restrict__ W,        // [OUTD, EMB]
    float* __restrict__ partial)        // [BATCH, CHUNKS, OUTD]
{
    // W staged as float4: wl[i] = (W0[2i], W0[2i+1], W1[2i], W1[2i+1])
    __shared__ float4 wl[EMB / 2];
    __shared__ float2 red[WAVES];

    const int tid = threadIdx.x;
    const int c = blockIdx.x;
    const int b = blockIdx.y;

    if (tid < EMB / 2) {
        wl[tid] = make_float4(W[2 * tid], W[2 * tid + 1],
                              W[EMB + 2 * tid], W[EMB + 2 * tid + 1]);
    }
    __syncthreads();

    float a0 = 0.0f, a1 = 0.0f;
    const int s = c * SPB + tid;
    if (tid < SPB && s < SEQ) {
        const int idx = t[b * SEQ + s];
        if (idx != -1) {   // -1 = padding, contributes 0
            const float2* __restrict__ row =
                (const float2*)(emb + (size_t)idx * EMB);
#pragma unroll
            for (int i = 0; i < EMB / 2; ++i) {
                float2 e = row[i];
                float4 w = wl[i];
                a0 = fmaf(e.x, w.x, fmaf(e.y, w.y, a0));
                a1 = fmaf(e.x, w.z, fmaf(e.y, w.w, a1));
            }
        }
    }

    // wave (64-lane) shuffle reduction
#pragma unroll
    for (int off = 32; off > 0; off >>= 1) {
        a0 += __shfl_down(a0, off, 64);
        a1 += __shfl_down(a1, off, 64);
    }
    const int wave = tid >> 6;
    const int lane = tid & 63;
    if (lane == 0) red[wave] = make_float2(a0, a1);
    __syncthreads();

    if (tid == 0) {
        float s0 = 0.0f, s1 = 0.0f;
#pragma unroll
        for (int w = 0; w < WAVES; ++w) { s0 += red[w].x; s1 += red[w].y; }
        float* p = partial + ((size_t)b * CHUNKS + c) * OUTD;
        p[0] = s0;
        p[1] = s1;
    }
}

// Kernel 2: one (b,o) pair per thread: sum CHUNKS partials, /BATCH, +bias, relu.
__global__ __launch_bounds__(TPB) void finalize_kernel(
    const float* __restrict__ partial,  // [BATCH, CHUNKS, OUTD]
    const float* __restrict__ bias,     // [OUTD]
    float* __restrict__ out)            // [BATCH, OUTD]
{
    const int i = threadIdx.x;
    if (i < BATCH * OUTD) {
        const int b = i >> 1;
        const int o = i & 1;
        float s = 0.0f;
#pragma unroll
        for (int c = 0; c < CHUNKS; ++c)
            s += partial[((size_t)b * CHUNKS + c) * OUTD + o];
        s = s * (1.0f / (float)BATCH) + bias[o];
        out[i] = fmaxf(s, 0.0f);
    }
}

extern "C" void kernel_launch(void* const* d_in, const int* in_sizes, int n_in,
                              void* d_out, int out_size, void* d_ws, size_t ws_size,
                              hipStream_t stream) {
    const int*   t    = (const int*)d_in[0];
    const float* emb  = (const float*)d_in[1];
    const float* W    = (const float*)d_in[2];
    const float* bias = (const float*)d_in[3];
    float* out        = (float*)d_out;
    float* partial    = (float*)d_ws;   // BATCH*CHUNKS*OUTD floats = 8 KB

    dim3 grid(CHUNKS, BATCH);
    embbag_partial_kernel<<<grid, TPB, 0, stream>>>(t, emb, W, partial);
    finalize_kernel<<<1, TPB, 0, stream>>>(partial, bias, out);
}

// Round 2
// 252.089 us; speedup vs baseline: 1.0197x; 1.0197x over previous
//
#include <hip/hip_runtime.h>

// Problem constants (from reference)
#define BATCH 128
#define SEQ   2000
#define EMB   50          // 25 float2 per row
#define OUTD  2

// Tiling: 2 lanes cooperate on one embedding row.
#define CHUNKS 16                      // seq chunks per batch row
#define RPB    (SEQ / CHUNKS)          // 125 rows per block
#define TPB    256
#define WAVES  (TPB / 64)

// Kernel 1: block = (chunk c, batch b). Thread pair (2 lanes) handles one
// index: gathers the 50-float row as interleaved float2 loads (lane k reads
// elements k, k+2, ...), folding the 50->2 linear layer on the fly (W staged
// in LDS). Full-wave shuffle reduction sums everything (pairs included),
// then LDS-reduce across the 4 waves; partial (2 floats) -> ws.
__global__ __launch_bounds__(TPB) void embbag_partial_kernel(
    const int* __restrict__ t,          // [BATCH, SEQ]
    const float* __restrict__ emb,      // [VOCAB, EMB]
    const float* __restrict__ W,        // [OUTD, EMB]
    float* __restrict__ partial)        // [BATCH, CHUNKS, OUTD]
{
    // wl[i] = (W0[2i], W0[2i+1], W1[2i], W1[2i+1]) for float2 element i
    __shared__ float4 wl[EMB / 2];
    __shared__ float2 red[WAVES];

    const int tid = threadIdx.x;
    const int c = blockIdx.x;
    const int b = blockIdx.y;

    if (tid < EMB / 2) {
        wl[tid] = make_float4(W[2 * tid], W[2 * tid + 1],
                              W[EMB + 2 * tid], W[EMB + 2 * tid + 1]);
    }
    __syncthreads();

    float a0 = 0.0f, a1 = 0.0f;
    const int pair = tid >> 1;          // row slot within block (0..127)
    const int k    = tid & 1;           // lane-within-pair
    if (pair < RPB) {
        const int s = c * RPB + pair;   // < SEQ by construction
        const int idx = t[b * SEQ + s];
        if (idx != -1) {                // -1 = padding, contributes 0
            const float2* __restrict__ row =
                (const float2*)(emb + (size_t)idx * EMB);
#pragma unroll
            for (int i = 0; i < 12; ++i) {
                float2 e = row[2 * i + k];
                float4 w = wl[2 * i + k];
                a0 = fmaf(e.x, w.x, fmaf(e.y, w.y, a0));
                a1 = fmaf(e.x, w.z, fmaf(e.y, w.w, a1));
            }
            if (k == 0) {               // odd tail: element 24
                float2 e = row[24];
                float4 w = wl[24];
                a0 = fmaf(e.x, w.x, fmaf(e.y, w.y, a0));
                a1 = fmaf(e.x, w.z, fmaf(e.y, w.w, a1));
            }
        }
    }

    // wave (64-lane) shuffle reduction — sums pair halves too
#pragma unroll
    for (int off = 32; off > 0; off >>= 1) {
        a0 += __shfl_down(a0, off, 64);
        a1 += __shfl_down(a1, off, 64);
    }
    const int wave = tid >> 6;
    const int lane = tid & 63;
    if (lane == 0) red[wave] = make_float2(a0, a1);
    __syncthreads();

    if (tid == 0) {
        float s0 = 0.0f, s1 = 0.0f;
#pragma unroll
        for (int w = 0; w < WAVES; ++w) { s0 += red[w].x; s1 += red[w].y; }
        float* p = partial + ((size_t)b * CHUNKS + c) * OUTD;
        p[0] = s0;
        p[1] = s1;
    }
}

// Kernel 2: one (b,o) pair per thread: sum CHUNKS partials, /BATCH, +bias, relu.
__global__ __launch_bounds__(TPB) void finalize_kernel(
    const float* __restrict__ partial,  // [BATCH, CHUNKS, OUTD]
    const float* __restrict__ bias,     // [OUTD]
    float* __restrict__ out)            // [BATCH, OUTD]
{
    const int i = threadIdx.x;
    if (i < BATCH * OUTD) {
        const int b = i >> 1;
        const int o = i & 1;
        float s = 0.0f;
#pragma unroll
        for (int c = 0; c < CHUNKS; ++c)
            s += partial[((size_t)b * CHUNKS + c) * OUTD + o];
        s = s * (1.0f / (float)BATCH) + bias[o];
        out[i] = fmaxf(s, 0.0f);
    }
}

extern "C" void kernel_launch(void* const* d_in, const int* in_sizes, int n_in,
                              void* d_out, int out_size, void* d_ws, size_t ws_size,
                              hipStream_t stream) {
    const int*   t    = (const int*)d_in[0];
    const float* emb  = (const float*)d_in[1];
    const float* W    = (const float*)d_in[2];
    const float* bias = (const float*)d_in[3];
    float* out        = (float*)d_out;
    float* partial    = (float*)d_ws;   // BATCH*CHUNKS*OUTD floats = 16 KB

    dim3 grid(CHUNKS, BATCH);
    embbag_partial_kernel<<<grid, TPB, 0, stream>>>(t, emb, W, partial);
    finalize_kernel<<<1, TPB, 0, stream>>>(partial, bias, out);
}